// Round 2
// baseline (226.967 us; speedup 1.0000x reference)
//
#include <hip/hip_runtime.h>

#define UU 128
#define HH 5120
#define RR 160
#define NS 32

// ---------------------------------------------------------------------------
// K1: dt_low partials.  dt_low = x(U,H) @ W_dt_low(H,R), split over 16 H-chunks.
// grid = 16 u-tiles * 16 h-chunks, 320 threads (r = t%160, half = t/160 -> 4 users)
// ---------------------------------------------------------------------------
__global__ __launch_bounds__(320) void k1_dtlow(const float* __restrict__ x,
                                                const float* __restrict__ Wdl,
                                                float* __restrict__ dtlP) {
    const int ut = blockIdx.x >> 4;   // 0..15
    const int hc = blockIdx.x & 15;   // 0..15, chunk of 320 h
    const int u0 = ut * 8;
    const int h0 = hc * 320;
    const int t  = threadIdx.x;
    __shared__ __attribute__((aligned(16))) float xs[320 * 8];  // [hh][ul]
    #pragma unroll
    for (int i = 0; i < 8; ++i)
        xs[t * 8 + i] = x[(u0 + i) * HH + h0 + t];
    __syncthreads();
    const int r    = t % 160;
    const int half = t / 160;         // 0 or 1 -> users half*4..half*4+3
    float a0 = 0.f, a1 = 0.f, a2 = 0.f, a3 = 0.f;
    const float* wp = Wdl + (size_t)h0 * RR + r;
    #pragma unroll 4
    for (int hh = 0; hh < 320; ++hh) {
        float w = wp[hh * RR];
        float4 xv = *(const float4*)&xs[hh * 8 + half * 4];
        a0 += xv.x * w; a1 += xv.y * w; a2 += xv.z * w; a3 += xv.w * w;
    }
    float* o = dtlP + hc * (UU * RR) + (u0 + half * 4) * RR + r;
    o[0] = a0; o[RR] = a1; o[2 * RR] = a2; o[3 * RR] = a3;
}

// ---------------------------------------------------------------------------
// K2b: B/C partials.  B = x@W_B, C = x@W_C  (both (H,N)).
// grid = 16 u-tiles * 8 h-chunks(640), 256 threads:
//   col = t&63 (n + B/C select), hq = t>>6 (4 sub-chunks of 160)
// ---------------------------------------------------------------------------
__global__ __launch_bounds__(256) void k2b_bc(const float* __restrict__ x,
                                              const float* __restrict__ WB,
                                              const float* __restrict__ WC,
                                              float* __restrict__ bcP) {
    const int ut = blockIdx.x >> 3;   // 0..15
    const int hc = blockIdx.x & 7;    // 0..7, chunk of 640 h
    const int u0 = ut * 8;
    const int h0 = hc * 640;
    const int t  = threadIdx.x;
    __shared__ __attribute__((aligned(16))) float xs[640 * 8];  // [hh][ul], 20KB
    for (int i = t; i < 640 * 8; i += 256) {
        int hh = i % 640, ul = i / 640;
        xs[hh * 8 + ul] = x[(u0 + ul) * HH + h0 + hh];
    }
    __syncthreads();
    const int col = t & 63, n = col & 31, mat = (col >> 5) & 1, hq = t >> 6;
    const float* W = (mat ? WC : WB) + (size_t)(h0 + hq * 160) * NS + n;
    float acc[8] = {0.f, 0.f, 0.f, 0.f, 0.f, 0.f, 0.f, 0.f};
    #pragma unroll 4
    for (int hh = 0; hh < 160; ++hh) {
        float w = W[hh * NS];
        const float* xp = &xs[(hq * 160 + hh) * 8];
        float4 a = *(const float4*)xp;
        float4 b = *(const float4*)(xp + 4);
        acc[0] += a.x * w; acc[1] += a.y * w; acc[2] += a.z * w; acc[3] += a.w * w;
        acc[4] += b.x * w; acc[5] += b.y * w; acc[6] += b.z * w; acc[7] += b.w * w;
    }
    __syncthreads();                       // xs reuse for hq-reduction
    #pragma unroll
    for (int ul = 0; ul < 8; ++ul) xs[t * 8 + ul] = acc[ul];
    __syncthreads();
    if (hq == 0) {
        #pragma unroll
        for (int ul = 0; ul < 8; ++ul) {
            float s = xs[t * 8 + ul] + xs[(t + 64) * 8 + ul]
                    + xs[(t + 128) * 8 + ul] + xs[(t + 192) * 8 + ul];
            bcP[hc * (UU * 64) + (u0 + ul) * 64 + col] = s;
        }
    }
}

// ---------------------------------------------------------------------------
// K2: delta = softplus(dt_low @ W_dt(R,H) + b_dt).  Also reduces B/C partials
// (ht==0 blocks).  grid = 16 u-tiles * 20 h-tiles(256), 256 threads.
// ---------------------------------------------------------------------------
__global__ __launch_bounds__(256) void k2_delta(const float* __restrict__ dtlP,
                                                const float* __restrict__ Wdt,
                                                const float* __restrict__ bdt,
                                                const float* __restrict__ bcP,
                                                float* __restrict__ BC,
                                                float* __restrict__ delta) {
    const int ut = blockIdx.x / 20;
    const int ht = blockIdx.x % 20;
    const int u0 = ut * 8, h0 = ht * 256, t = threadIdx.x;
    __shared__ __attribute__((aligned(16))) float dtl[RR * 8];  // [r][ul]
    for (int i = t; i < RR * 8; i += 256) {
        int r = i % RR, ul = i / RR;
        float s = 0.f;
        #pragma unroll
        for (int hc = 0; hc < 16; ++hc)
            s += dtlP[hc * (UU * RR) + (u0 + ul) * RR + r];
        dtl[r * 8 + ul] = s;
    }
    if (ht == 0) {
        for (int i = t; i < 512; i += 256) {
            int ul = i >> 6, col = i & 63;
            float s = 0.f;
            #pragma unroll
            for (int hc = 0; hc < 8; ++hc)
                s += bcP[hc * (UU * 64) + (u0 + ul) * 64 + col];
            BC[(u0 + ul) * 64 + col] = s;
        }
    }
    __syncthreads();
    const int h = h0 + t;
    float acc[8] = {0.f, 0.f, 0.f, 0.f, 0.f, 0.f, 0.f, 0.f};
    #pragma unroll 4
    for (int r = 0; r < RR; ++r) {
        float w = Wdt[(size_t)r * HH + h];
        float4 a = *(const float4*)&dtl[r * 8];
        float4 b = *(const float4*)&dtl[r * 8 + 4];
        acc[0] += a.x * w; acc[1] += a.y * w; acc[2] += a.z * w; acc[3] += a.w * w;
        acc[4] += b.x * w; acc[5] += b.y * w; acc[6] += b.z * w; acc[7] += b.w * w;
    }
    const float bv = bdt[h];
    #pragma unroll
    for (int ul = 0; ul < 8; ++ul) {
        float z = acc[ul] + bv;
        float d = (z > 20.f) ? z : __logf(1.f + __expf(z));
        delta[(size_t)(u0 + ul) * HH + h] = d;
    }
}

// ---------------------------------------------------------------------------
// K3: main streaming kernel.  One (u,h) pair per 8 lanes, each lane owns a
// float4 of the N=32 state dim.  h_prev/A reads fully coalesced (4KB/block).
// grid = U * (H/32) = 20480 blocks, 256 threads (32 pairs/block).
// ---------------------------------------------------------------------------
__global__ __launch_bounds__(256) void k3_main(const float* __restrict__ x,
                                               const float* __restrict__ hprev,
                                               const float* __restrict__ A,
                                               const float* __restrict__ Dp,
                                               const float* __restrict__ BC,
                                               const float* __restrict__ delta,
                                               float* __restrict__ out) {
    const int u  = blockIdx.x / 160;
    const int ht = blockIdx.x % 160;     // tile of 32 h
    const int t  = threadIdx.x;
    __shared__ __attribute__((aligned(16))) float bc[64];
    if (t < 64) bc[t] = BC[u * 64 + t];
    __syncthreads();
    const int g = t >> 3;                // pair within block: 0..31
    const int l = t & 7;                 // lane within pair
    const int h = ht * 32 + g;
    const float d  = delta[(size_t)u * HH + h];
    const float xv = x[(size_t)u * HH + h];
    const float4 a4 = *(const float4*)&A[(size_t)h * NS + l * 4];
    const float4 hp = *(const float4*)&hprev[((size_t)u * HH + h) * NS + l * 4];
    const float4 b4 = *(const float4*)&bc[l * 4];
    const float4 c4 = *(const float4*)&bc[32 + l * 4];
    const float dx = d * xv;
    float4 hn;
    hn.x = __expf(d * a4.x) * hp.x + dx * b4.x;
    hn.y = __expf(d * a4.y) * hp.y + dx * b4.y;
    hn.z = __expf(d * a4.z) * hp.z + dx * b4.z;
    hn.w = __expf(d * a4.w) * hp.w + dx * b4.w;
    float y = hn.x * c4.x + hn.y * c4.y + hn.z * c4.z + hn.w * c4.w;
    y += __shfl_xor(y, 1);
    y += __shfl_xor(y, 2);
    y += __shfl_xor(y, 4);
    if (l == 0) out[(size_t)u * HH + h] = xv * Dp[h] + y;
}

// ---------------------------------------------------------------------------
extern "C" void kernel_launch(void* const* d_in, const int* in_sizes, int n_in,
                              void* d_out, int out_size, void* d_ws, size_t ws_size,
                              hipStream_t stream) {
    const float* x     = (const float*)d_in[0];
    const float* hprev = (const float*)d_in[1];
    const float* Wdl   = (const float*)d_in[2];
    const float* Wdt   = (const float*)d_in[3];
    const float* bdt   = (const float*)d_in[4];
    const float* WB    = (const float*)d_in[5];
    const float* WC    = (const float*)d_in[6];
    const float* A     = (const float*)d_in[7];
    const float* Dp    = (const float*)d_in[8];
    float* out = (float*)d_out;
    float* ws  = (float*)d_ws;

    float* dtlP  = ws;            // 16*128*160 = 327680 floats
    float* bcP   = ws + 327680;   // 8*128*64   =  65536 floats
    float* BC    = ws + 393216;   // 128*64     =   8192 floats
    float* delta = ws + 401408;   // 128*5120   = 655360 floats  (total ~4.03MB)

    k1_dtlow<<<256, 320, 0, stream>>>(x, Wdl, dtlP);
    k2b_bc  <<<128, 256, 0, stream>>>(x, WB, WC, bcP);
    k2_delta<<<320, 256, 0, stream>>>(dtlP, Wdt, bdt, bcP, BC, delta);
    k3_main <<<20480, 256, 0, stream>>>(x, hprev, A, Dp, BC, delta, out);
}

// Round 4
// 214.905 us; speedup vs baseline: 1.0561x; 1.0561x over previous
//
#include <hip/hip_runtime.h>

#define UU 128
#define HH 5120
#define RR 160
#define NS 32

// ---------------------------------------------------------------------------
// KA: fused projection partials.  dt_low = x@W_dt_low (U,R), B = x@W_B (U,32),
// C = x@W_C (U,32) — all share one x-tile staged in LDS.
// grid = 16 u-tiles(8u) * 32 h-chunks(160h) = 512 blocks, 256 threads.
// thread c: c<160 -> dt_low col c; 160<=c<224 -> B/C col; c>=224 idle.
// partial layouts: dtlP[hc][r(160)][u(128)], bcP[hc][col(64)][u(128)].
// ---------------------------------------------------------------------------
__global__ __launch_bounds__(256) void ka_proj(const float* __restrict__ x,
                                               const float* __restrict__ Wdl,
                                               const float* __restrict__ WB,
                                               const float* __restrict__ WC,
                                               float* __restrict__ dtlP,
                                               float* __restrict__ bcP) {
    const int ut = blockIdx.x >> 5;   // 0..15
    const int hc = blockIdx.x & 31;   // 0..31
    const int u0 = ut * 8;
    const int h0 = hc * 160;
    const int t  = threadIdx.x;
    __shared__ __attribute__((aligned(16))) float xs[160 * 8];  // [hh][ul], 5KB
    #pragma unroll
    for (int k = 0; k < 5; ++k) {
        int i  = t + k * 256;
        int ul = i / 160, hh = i % 160;      // consecutive i -> consecutive hh
        xs[hh * 8 + ul] = x[(u0 + ul) * HH + h0 + hh];
    }
    __syncthreads();
    const int c = t;
    const float* wp;
    int stride;
    float* outp = nullptr;
    if (c < 160) {
        wp = Wdl + (size_t)h0 * RR + c;          stride = RR;
        outp = dtlP + hc * (RR * UU) + c * UU + u0;
    } else if (c < 224) {
        int col = c - 160;                        // 0..31 = B, 32..63 = C
        wp = ((col < 32) ? WB : WC) + (size_t)h0 * NS + (col & 31);
        stride = NS;
        outp = bcP + hc * (64 * UU) + col * UU + u0;
    } else {
        wp = Wdl; stride = 0;                     // idle lanes: safe broadcast
    }
    float a[8] = {0.f, 0.f, 0.f, 0.f, 0.f, 0.f, 0.f, 0.f};
    #pragma unroll 4
    for (int hh = 0; hh < 160; ++hh) {
        float w = wp[hh * stride];
        float4 x0 = *(const float4*)&xs[hh * 8];
        float4 x1 = *(const float4*)&xs[hh * 8 + 4];
        a[0] += x0.x * w; a[1] += x0.y * w; a[2] += x0.z * w; a[3] += x0.w * w;
        a[4] += x1.x * w; a[5] += x1.y * w; a[6] += x1.z * w; a[7] += x1.w * w;
    }
    if (outp) {
        *(float4*)&outp[0] = make_float4(a[0], a[1], a[2], a[3]);
        *(float4*)&outp[4] = make_float4(a[4], a[5], a[6], a[7]);
    }
}

// ---------------------------------------------------------------------------
// KB: delta = softplus(dt_low @ W_dt(R,H) + b_dt); ht==0 blocks also reduce
// the B/C partials into BC[u][64].  grid = 16 ut * 20 ht(256h) = 320 blocks.
// ---------------------------------------------------------------------------
__global__ __launch_bounds__(256) void kb_delta(const float* __restrict__ dtlP,
                                                const float* __restrict__ Wdt,
                                                const float* __restrict__ bdt,
                                                const float* __restrict__ bcP,
                                                float* __restrict__ BC,
                                                float* __restrict__ delta) {
    const int ut = blockIdx.x / 20;
    const int ht = blockIdx.x % 20;
    const int u0 = ut * 8, h0 = ht * 256, t = threadIdx.x;
    __shared__ __attribute__((aligned(16))) float dtl[RR * 8];  // [r][ul]
    #pragma unroll
    for (int k = 0; k < 5; ++k) {
        int i = t + k * 256;
        int r = i >> 3, ul = i & 7;              // ul fastest -> 32B runs
        float s = 0.f;
        #pragma unroll
        for (int hc = 0; hc < 32; ++hc)
            s += dtlP[hc * (RR * UU) + r * UU + u0 + ul];
        dtl[i] = s;
    }
    if (ht == 0) {
        #pragma unroll
        for (int k = 0; k < 2; ++k) {
            int i = t + k * 256;
            int ul = i >> 6, col = i & 63;
            float s = 0.f;
            #pragma unroll
            for (int hc = 0; hc < 32; ++hc)
                s += bcP[hc * (64 * UU) + col * UU + u0 + ul];
            BC[(u0 + ul) * 64 + col] = s;
        }
    }
    __syncthreads();
    const int h = h0 + t;
    float acc[8] = {0.f, 0.f, 0.f, 0.f, 0.f, 0.f, 0.f, 0.f};
    #pragma unroll 4
    for (int r = 0; r < RR; ++r) {
        float w = Wdt[(size_t)r * HH + h];
        float4 a = *(const float4*)&dtl[r * 8];
        float4 b = *(const float4*)&dtl[r * 8 + 4];
        acc[0] += a.x * w; acc[1] += a.y * w; acc[2] += a.z * w; acc[3] += a.w * w;
        acc[4] += b.x * w; acc[5] += b.y * w; acc[6] += b.z * w; acc[7] += b.w * w;
    }
    const float bv = bdt[h];
    #pragma unroll
    for (int ul = 0; ul < 8; ++ul) {
        float z = acc[ul] + bv;
        float d = (z > 20.f) ? z : __logf(1.f + __expf(z));
        delta[(size_t)(u0 + ul) * HH + h] = d;
    }
}

// ---------------------------------------------------------------------------
// KC: main streaming kernel, thread-per-(u,h).  Each lane owns one 128-byte
// h_prev row (one cacheline) via 8 independent float4 loads; A likewise
// (L2-resident after first u).  No shuffles; coalesced scalar store.
// grid = 128 u * 20 ht(256h) = 2560 blocks, 256 threads.
// ---------------------------------------------------------------------------
__global__ __launch_bounds__(256) void kc_main(const float* __restrict__ x,
                                               const float* __restrict__ hprev,
                                               const float* __restrict__ A,
                                               const float* __restrict__ Dp,
                                               const float* __restrict__ BC,
                                               const float* __restrict__ delta,
                                               float* __restrict__ out) {
    const int u  = blockIdx.x / 20;
    const int ht = blockIdx.x % 20;
    const int t  = threadIdx.x;
    __shared__ __attribute__((aligned(16))) float bc[64];
    if (t < 64) bc[t] = BC[u * 64 + t];
    __syncthreads();
    const int h = ht * 256 + t;
    const float d  = delta[(size_t)u * HH + h];
    const float xv = x[(size_t)u * HH + h];
    const float dx = d * xv;
    const float4* hp = (const float4*)&hprev[((size_t)u * HH + h) * NS];
    const float4* ap = (const float4*)&A[(size_t)h * NS];
    float y = 0.f;
    #pragma unroll
    for (int j = 0; j < 8; ++j) {
        float4 a4 = ap[j];
        float4 h4 = hp[j];
        float4 b4 = *(const float4*)&bc[j * 4];
        float4 c4 = *(const float4*)&bc[32 + j * 4];
        float n0 = __expf(d * a4.x) * h4.x + dx * b4.x;
        float n1 = __expf(d * a4.y) * h4.y + dx * b4.y;
        float n2 = __expf(d * a4.z) * h4.z + dx * b4.z;
        float n3 = __expf(d * a4.w) * h4.w + dx * b4.w;
        y += n0 * c4.x + n1 * c4.y + n2 * c4.z + n3 * c4.w;
    }
    out[(size_t)u * HH + h] = xv * Dp[h] + y;
}

// ---------------------------------------------------------------------------
extern "C" void kernel_launch(void* const* d_in, const int* in_sizes, int n_in,
                              void* d_out, int out_size, void* d_ws, size_t ws_size,
                              hipStream_t stream) {
    const float* x     = (const float*)d_in[0];
    const float* hprev = (const float*)d_in[1];
    const float* Wdl   = (const float*)d_in[2];
    const float* Wdt   = (const float*)d_in[3];
    const float* bdt   = (const float*)d_in[4];
    const float* WB    = (const float*)d_in[5];
    const float* WC    = (const float*)d_in[6];
    const float* A     = (const float*)d_in[7];
    const float* Dp    = (const float*)d_in[8];
    float* out = (float*)d_out;
    float* ws  = (float*)d_ws;

    float* dtlP  = ws;            // 32*160*128 = 655360 floats
    float* bcP   = ws + 655360;   // 32*64*128  = 262144 floats
    float* BC    = ws + 917504;   // 128*64     =   8192 floats
    float* delta = ws + 925696;   // 128*5120   = 655360 floats  (~6.0 MB total)

    ka_proj <<<512,  256, 0, stream>>>(x, Wdl, WB, WC, dtlP, bcP);
    kb_delta<<<320,  256, 0, stream>>>(dtlP, Wdt, bdt, bcP, BC, delta);
    kc_main <<<2560, 256, 0, stream>>>(x, hprev, A, Dp, BC, delta, out);
}

// Round 5
// 207.092 us; speedup vs baseline: 1.0960x; 1.0377x over previous
//
#include <hip/hip_runtime.h>

#define UU 128
#define HH 5120
#define RR 160
#define NS 32

// ---------------------------------------------------------------------------
// KA: fused projection partials.  dt_low = x@W_dt_low (U,R), B = x@W_B (U,32),
// C = x@W_C (U,32) — all share one x-tile staged in LDS.
// grid = 16 u-tiles(8u) * 32 h-chunks(160h) = 512 blocks, 256 threads.
// thread c: c<160 -> dt_low col c; 160<=c<224 -> B/C col; c>=224 idle.
// partial layouts: dtlP[hc][r(160)][u(128)], bcP[hc][col(64)][u(128)].
// ---------------------------------------------------------------------------
__global__ __launch_bounds__(256) void ka_proj(const float* __restrict__ x,
                                               const float* __restrict__ Wdl,
                                               const float* __restrict__ WB,
                                               const float* __restrict__ WC,
                                               float* __restrict__ dtlP,
                                               float* __restrict__ bcP) {
    const int ut = blockIdx.x >> 5;   // 0..15
    const int hc = blockIdx.x & 31;   // 0..31
    const int u0 = ut * 8;
    const int h0 = hc * 160;
    const int t  = threadIdx.x;
    __shared__ __attribute__((aligned(16))) float xs[160 * 8];  // [hh][ul], 5KB
    #pragma unroll
    for (int k = 0; k < 5; ++k) {
        int i  = t + k * 256;
        int ul = i / 160, hh = i % 160;      // consecutive i -> consecutive hh
        xs[hh * 8 + ul] = x[(u0 + ul) * HH + h0 + hh];
    }
    __syncthreads();
    const int c = t;
    const float* wp;
    int stride;
    float* outp = nullptr;
    if (c < 160) {
        wp = Wdl + (size_t)h0 * RR + c;          stride = RR;
        outp = dtlP + hc * (RR * UU) + c * UU + u0;
    } else if (c < 224) {
        int col = c - 160;                        // 0..31 = B, 32..63 = C
        wp = ((col < 32) ? WB : WC) + (size_t)h0 * NS + (col & 31);
        stride = NS;
        outp = bcP + hc * (64 * UU) + col * UU + u0;
    } else {
        wp = Wdl; stride = 0;                     // idle lanes: safe broadcast
    }
    float a[8] = {0.f, 0.f, 0.f, 0.f, 0.f, 0.f, 0.f, 0.f};
    #pragma unroll 4
    for (int hh = 0; hh < 160; ++hh) {
        float w = wp[hh * stride];
        float4 x0 = *(const float4*)&xs[hh * 8];
        float4 x1 = *(const float4*)&xs[hh * 8 + 4];
        a[0] += x0.x * w; a[1] += x0.y * w; a[2] += x0.z * w; a[3] += x0.w * w;
        a[4] += x1.x * w; a[5] += x1.y * w; a[6] += x1.z * w; a[7] += x1.w * w;
    }
    if (outp) {
        *(float4*)&outp[0] = make_float4(a[0], a[1], a[2], a[3]);
        *(float4*)&outp[4] = make_float4(a[4], a[5], a[6], a[7]);
    }
}

// ---------------------------------------------------------------------------
// KB: delta = softplus(dt_low @ W_dt(R,H) + b_dt); ht==0 blocks also reduce
// the B/C partials into BC[u][64].  grid = 16 ut * 20 ht(256h) = 320 blocks.
// ---------------------------------------------------------------------------
__global__ __launch_bounds__(256) void kb_delta(const float* __restrict__ dtlP,
                                                const float* __restrict__ Wdt,
                                                const float* __restrict__ bdt,
                                                const float* __restrict__ bcP,
                                                float* __restrict__ BC,
                                                float* __restrict__ delta) {
    const int ut = blockIdx.x / 20;
    const int ht = blockIdx.x % 20;
    const int u0 = ut * 8, h0 = ht * 256, t = threadIdx.x;
    __shared__ __attribute__((aligned(16))) float dtl[RR * 8];  // [r][ul]
    #pragma unroll
    for (int k = 0; k < 5; ++k) {
        int i = t + k * 256;
        int r = i >> 3, ul = i & 7;              // ul fastest -> 32B runs
        float s = 0.f;
        #pragma unroll
        for (int hc = 0; hc < 32; ++hc)
            s += dtlP[hc * (RR * UU) + r * UU + u0 + ul];
        dtl[i] = s;
    }
    if (ht == 0) {
        #pragma unroll
        for (int k = 0; k < 2; ++k) {
            int i = t + k * 256;
            int ul = i >> 6, col = i & 63;
            float s = 0.f;
            #pragma unroll
            for (int hc = 0; hc < 32; ++hc)
                s += bcP[hc * (64 * UU) + col * UU + u0 + ul];
            BC[(u0 + ul) * 64 + col] = s;
        }
    }
    __syncthreads();
    const int h = h0 + t;
    float acc[8] = {0.f, 0.f, 0.f, 0.f, 0.f, 0.f, 0.f, 0.f};
    #pragma unroll 4
    for (int r = 0; r < RR; ++r) {
        float w = Wdt[(size_t)r * HH + h];
        float4 a = *(const float4*)&dtl[r * 8];
        float4 b = *(const float4*)&dtl[r * 8 + 4];
        acc[0] += a.x * w; acc[1] += a.y * w; acc[2] += a.z * w; acc[3] += a.w * w;
        acc[4] += b.x * w; acc[5] += b.y * w; acc[6] += b.z * w; acc[7] += b.w * w;
    }
    const float bv = bdt[h];
    #pragma unroll
    for (int ul = 0; ul < 8; ++ul) {
        float z = acc[ul] + bv;
        float d = (z > 20.f) ? z : __logf(1.f + __expf(z));
        delta[(size_t)(u0 + ul) * HH + h] = d;
    }
}

// ---------------------------------------------------------------------------
// KC: main streaming kernel.  8 lanes per (u,h) pair, lane owns a float4 of
// the N=32 state dim -> every h_prev/A load instruction is 1KB contiguous
// per wave (fully coalesced, no L1 reliance).  Block (u, ht) covers 256 h
// via 8 independent sub-tile iterations (load ILP); BC hoisted to registers.
// grid = 128 u * 20 ht = 2560 blocks, 256 threads.
// ---------------------------------------------------------------------------
__global__ __launch_bounds__(256) void kc_main(const float* __restrict__ x,
                                               const float* __restrict__ hprev,
                                               const float* __restrict__ A,
                                               const float* __restrict__ Dp,
                                               const float* __restrict__ BC,
                                               const float* __restrict__ delta,
                                               float* __restrict__ out) {
    const int u  = blockIdx.x / 20;
    const int ht = blockIdx.x % 20;
    const int t  = threadIdx.x;
    __shared__ __attribute__((aligned(16))) float bc[64];
    if (t < 64) bc[t] = BC[u * 64 + t];
    __syncthreads();
    const int g = t >> 3;                // pair-in-subtile: 0..31
    const int l = t & 7;                 // lane within pair
    const float4 b4 = *(const float4*)&bc[l * 4];
    const float4 c4 = *(const float4*)&bc[32 + l * 4];
    #pragma unroll
    for (int i = 0; i < 8; ++i) {
        const int h = ht * 256 + i * 32 + g;
        const float d  = delta[(size_t)u * HH + h];
        const float xv = x[(size_t)u * HH + h];
        const float4 a4 = *(const float4*)&A[(size_t)h * NS + l * 4];
        const float4 hp = *(const float4*)&hprev[((size_t)u * HH + h) * NS + l * 4];
        const float dx = d * xv;
        float4 hn;
        hn.x = __expf(d * a4.x) * hp.x + dx * b4.x;
        hn.y = __expf(d * a4.y) * hp.y + dx * b4.y;
        hn.z = __expf(d * a4.z) * hp.z + dx * b4.z;
        hn.w = __expf(d * a4.w) * hp.w + dx * b4.w;
        float y = hn.x * c4.x + hn.y * c4.y + hn.z * c4.z + hn.w * c4.w;
        y += __shfl_xor(y, 1);
        y += __shfl_xor(y, 2);
        y += __shfl_xor(y, 4);
        if (l == 0) out[(size_t)u * HH + h] = xv * Dp[h] + y;
    }
}

// ---------------------------------------------------------------------------
extern "C" void kernel_launch(void* const* d_in, const int* in_sizes, int n_in,
                              void* d_out, int out_size, void* d_ws, size_t ws_size,
                              hipStream_t stream) {
    const float* x     = (const float*)d_in[0];
    const float* hprev = (const float*)d_in[1];
    const float* Wdl   = (const float*)d_in[2];
    const float* Wdt   = (const float*)d_in[3];
    const float* bdt   = (const float*)d_in[4];
    const float* WB    = (const float*)d_in[5];
    const float* WC    = (const float*)d_in[6];
    const float* A     = (const float*)d_in[7];
    const float* Dp    = (const float*)d_in[8];
    float* out = (float*)d_out;
    float* ws  = (float*)d_ws;

    float* dtlP  = ws;            // 32*160*128 = 655360 floats
    float* bcP   = ws + 655360;   // 32*64*128  = 262144 floats
    float* BC    = ws + 917504;   // 128*64     =   8192 floats
    float* delta = ws + 925696;   // 128*5120   = 655360 floats  (~6.0 MB total)

    ka_proj <<<512,  256, 0, stream>>>(x, Wdl, WB, WC, dtlP, bcP);
    kb_delta<<<320,  256, 0, stream>>>(dtlP, Wdt, bdt, bcP, BC, delta);
    kc_main <<<2560, 256, 0, stream>>>(x, hprev, A, Dp, BC, delta, out);
}

// Round 8
// 192.710 us; speedup vs baseline: 1.1778x; 1.0746x over previous
//
#include <hip/hip_runtime.h>

#define UU 128
#define HH 5120
#define RR 160
#define NS 32

// ---------------------------------------------------------------------------
// KA: fused projection partials.  dt_low = x@W_dt_low (U,R), B = x@W_B (U,32),
// C = x@W_C (U,32) — all share one x-tile staged in LDS.
// grid = 16 u-tiles(8u) * 32 h-chunks(160h) = 512 blocks, 256 threads.
// thread c: c<160 -> dt_low col c; 160<=c<224 -> B/C col; c>=224 idle.
// partial layouts (u-major for coalesced KB reads):
//   dtlP[hc][u(128)][r(160)], bcP[hc][u(128)][col(64)].
// ---------------------------------------------------------------------------
__global__ __launch_bounds__(256) void ka_proj(const float* __restrict__ x,
                                               const float* __restrict__ Wdl,
                                               const float* __restrict__ WB,
                                               const float* __restrict__ WC,
                                               float* __restrict__ dtlP,
                                               float* __restrict__ bcP) {
    const int ut = blockIdx.x >> 5;   // 0..15
    const int hc = blockIdx.x & 31;   // 0..31
    const int u0 = ut * 8;
    const int h0 = hc * 160;
    const int t  = threadIdx.x;
    __shared__ __attribute__((aligned(16))) float xs[160 * 8];  // [hh][ul], 5KB
    #pragma unroll
    for (int k = 0; k < 5; ++k) {
        int i  = t + k * 256;
        int ul = i / 160, hh = i % 160;      // consecutive i -> consecutive hh
        xs[hh * 8 + ul] = x[(u0 + ul) * HH + h0 + hh];
    }
    __syncthreads();
    const int c = t;
    const float* wp;
    int stride;
    if (c < 160) {
        wp = Wdl + (size_t)h0 * RR + c;          stride = RR;
    } else if (c < 224) {
        int col = c - 160;                        // 0..31 = B, 32..63 = C
        wp = ((col < 32) ? WB : WC) + (size_t)h0 * NS + (col & 31);
        stride = NS;
    } else {
        wp = Wdl; stride = 0;                     // idle lanes: safe broadcast
    }
    float a[8] = {0.f, 0.f, 0.f, 0.f, 0.f, 0.f, 0.f, 0.f};
    #pragma unroll 4
    for (int hh = 0; hh < 160; ++hh) {
        float w = wp[hh * stride];
        float4 x0 = *(const float4*)&xs[hh * 8];
        float4 x1 = *(const float4*)&xs[hh * 8 + 4];
        a[0] += x0.x * w; a[1] += x0.y * w; a[2] += x0.z * w; a[3] += x0.w * w;
        a[4] += x1.x * w; a[5] += x1.y * w; a[6] += x1.z * w; a[7] += x1.w * w;
    }
    if (c < 160) {
        float* o = dtlP + hc * (UU * RR) + u0 * RR + c;   // lanes c: contiguous
        #pragma unroll
        for (int j = 0; j < 8; ++j) o[j * RR] = a[j];
    } else if (c < 224) {
        int col = c - 160;
        float* o = bcP + hc * (UU * 64) + u0 * 64 + col;  // lanes col: contiguous
        #pragma unroll
        for (int j = 0; j < 8; ++j) o[j * 64] = a[j];
    }
}

// ---------------------------------------------------------------------------
// KB: delta = softplus(dt_low @ W_dt(R,H) + b_dt); ht==0 blocks also reduce
// the B/C partials into BC[u][64].  grid = 16 ut * 20 ht(256h) = 320 blocks.
// Partial reads now fully coalesced (r / col fastest, contiguous per wave).
// ---------------------------------------------------------------------------
__global__ __launch_bounds__(256) void kb_delta(const float* __restrict__ dtlP,
                                                const float* __restrict__ Wdt,
                                                const float* __restrict__ bdt,
                                                const float* __restrict__ bcP,
                                                float* __restrict__ BC,
                                                float* __restrict__ delta) {
    const int ut = blockIdx.x / 20;
    const int ht = blockIdx.x % 20;
    const int u0 = ut * 8, h0 = ht * 256, t = threadIdx.x;
    __shared__ __attribute__((aligned(16))) float dtl[RR * 8];  // [r][ul]
    #pragma unroll
    for (int k = 0; k < 5; ++k) {
        int i = t + k * 256;
        int r = i % 160, ul = i / 160;           // consecutive lanes -> consecutive r
        float s = 0.f;
        #pragma unroll
        for (int hc = 0; hc < 32; ++hc)
            s += dtlP[hc * (UU * RR) + (u0 + ul) * RR + r];
        dtl[r * 8 + ul] = s;
    }
    if (ht == 0) {
        #pragma unroll
        for (int k = 0; k < 2; ++k) {
            int i = t + k * 256;
            int col = i & 63, ul = i >> 6;       // consecutive lanes -> consecutive col
            float s = 0.f;
            #pragma unroll
            for (int hc = 0; hc < 32; ++hc)
                s += bcP[hc * (UU * 64) + (u0 + ul) * 64 + col];
            BC[(u0 + ul) * 64 + col] = s;
        }
    }
    __syncthreads();
    const int h = h0 + t;
    float acc[8] = {0.f, 0.f, 0.f, 0.f, 0.f, 0.f, 0.f, 0.f};
    #pragma unroll 4
    for (int r = 0; r < RR; ++r) {
        float w = Wdt[(size_t)r * HH + h];
        float4 a = *(const float4*)&dtl[r * 8];
        float4 b = *(const float4*)&dtl[r * 8 + 4];
        acc[0] += a.x * w; acc[1] += a.y * w; acc[2] += a.z * w; acc[3] += a.w * w;
        acc[4] += b.x * w; acc[5] += b.y * w; acc[6] += b.z * w; acc[7] += b.w * w;
    }
    const float bv = bdt[h];
    #pragma unroll
    for (int ul = 0; ul < 8; ++ul) {
        float z = acc[ul] + bv;
        float d = (z > 20.f) ? z : __logf(1.f + __expf(z));
        delta[(size_t)(u0 + ul) * HH + h] = d;
    }
}

// ---------------------------------------------------------------------------
// KC: main streaming kernel.  8 lanes per (u,h) pair, lane owns a float4 of
// the N=32 state dim -> every h_prev/A load instruction is 1KB contiguous
// per wave (fully coalesced, no L1 reliance).  Block (u, ht) covers 256 h
// via 8 independent sub-tile iterations (load ILP); BC hoisted to registers.
// grid = 128 u * 20 ht = 2560 blocks, 256 threads.
// ---------------------------------------------------------------------------
__global__ __launch_bounds__(256) void kc_main(const float* __restrict__ x,
                                               const float* __restrict__ hprev,
                                               const float* __restrict__ A,
                                               const float* __restrict__ Dp,
                                               const float* __restrict__ BC,
                                               const float* __restrict__ delta,
                                               float* __restrict__ out) {
    const int u  = blockIdx.x / 20;
    const int ht = blockIdx.x % 20;
    const int t  = threadIdx.x;
    __shared__ __attribute__((aligned(16))) float bc[64];
    if (t < 64) bc[t] = BC[u * 64 + t];
    __syncthreads();
    const int g = t >> 3;                // pair-in-subtile: 0..31
    const int l = t & 7;                 // lane within pair
    const float4 b4 = *(const float4*)&bc[l * 4];
    const float4 c4 = *(const float4*)&bc[32 + l * 4];
    #pragma unroll
    for (int i = 0; i < 8; ++i) {
        const int h = ht * 256 + i * 32 + g;
        const float d  = delta[(size_t)u * HH + h];
        const float xv = x[(size_t)u * HH + h];
        const float4 a4 = *(const float4*)&A[(size_t)h * NS + l * 4];
        const float4 hp = *(const float4*)&hprev[((size_t)u * HH + h) * NS + l * 4];
        const float dx = d * xv;
        float4 hn;
        hn.x = __expf(d * a4.x) * hp.x + dx * b4.x;
        hn.y = __expf(d * a4.y) * hp.y + dx * b4.y;
        hn.z = __expf(d * a4.z) * hp.z + dx * b4.z;
        hn.w = __expf(d * a4.w) * hp.w + dx * b4.w;
        float y = hn.x * c4.x + hn.y * c4.y + hn.z * c4.z + hn.w * c4.w;
        y += __shfl_xor(y, 1);
        y += __shfl_xor(y, 2);
        y += __shfl_xor(y, 4);
        if (l == 0) out[(size_t)u * HH + h] = xv * Dp[h] + y;
    }
}

// ---------------------------------------------------------------------------
extern "C" void kernel_launch(void* const* d_in, const int* in_sizes, int n_in,
                              void* d_out, int out_size, void* d_ws, size_t ws_size,
                              hipStream_t stream) {
    const float* x     = (const float*)d_in[0];
    const float* hprev = (const float*)d_in[1];
    const float* Wdl   = (const float*)d_in[2];
    const float* Wdt   = (const float*)d_in[3];
    const float* bdt   = (const float*)d_in[4];
    const float* WB    = (const float*)d_in[5];
    const float* WC    = (const float*)d_in[6];
    const float* A     = (const float*)d_in[7];
    const float* Dp    = (const float*)d_in[8];
    float* out = (float*)d_out;
    float* ws  = (float*)d_ws;

    float* dtlP  = ws;            // 32*128*160 = 655360 floats  [hc][u][r]
    float* bcP   = ws + 655360;   // 32*128*64  = 262144 floats  [hc][u][col]
    float* BC    = ws + 917504;   // 128*64     =   8192 floats
    float* delta = ws + 925696;   // 128*5120   = 655360 floats  (~6.0 MB total)

    ka_proj <<<512,  256, 0, stream>>>(x, Wdl, WB, WC, dtlP, bcP);
    kb_delta<<<320,  256, 0, stream>>>(dtlP, Wdt, bdt, bcP, BC, delta);
    kc_main <<<2560, 256, 0, stream>>>(x, hprev, A, Dp, BC, delta, out);
}